// Round 5
// baseline (90.448 us; speedup 1.0000x reference)
//
#include <hip/hip_runtime.h>
#include <hip/hip_bf16.h>

#define NFFT    1024
#define HOPSZ   256
#define XLEN    262144
#define PADLEN  (XLEN + NFFT)      // 263168
#define NBATCH  16
#define NBINS2  1026
#define FBIN    513
#define NFRAMES 1025
#define NGF     (NBATCH * NFRAMES) // 16400
#define TOTOUT  ((size_t)NBATCH * FBIN * NFRAMES)

// GEMM geometry: BM=256 x BN=256, BK=64, 8 waves (2M x 4N), per-wave 128x64
#define KT 64
#define NKT 16
#define NT_TILES 64                // gf 0..16383 exactly
#define MT_TILES 4                 // bins 0..1023 exactly
#define NWG (MT_TILES * NT_TILES)  // 256
#define ABYTES 32768               // 256 rows x 128 B
#define BUFE   32768               // elems per buffer (A 16384 + B 16384)
#define BUFB   65536               // bytes per buffer
#define NTAIL  49184               // 2*16400 + 16*1024

typedef short bf16x8 __attribute__((ext_vector_type(8)));
typedef float f32x4  __attribute__((ext_vector_type(4)));
typedef unsigned short u16x8 __attribute__((ext_vector_type(8)));
typedef unsigned short u16x4 __attribute__((ext_vector_type(4)));

__device__ __forceinline__ unsigned short f2bf(float f) {
  union { float f; unsigned u; } v; v.f = f;
  unsigned r = v.u + 0x7fffu + ((v.u >> 16) & 1u);   // RNE
  return (unsigned short)(r >> 16);
}
__device__ __forceinline__ float bf2f(unsigned short h) {
  union { unsigned u; float f; } v; v.u = ((unsigned)h) << 16; return v.f;
}

typedef __attribute__((address_space(1))) void void_g;
typedef __attribute__((address_space(3))) void void_l;
__device__ __forceinline__ void gload_lds16(const void* g, void* l) {
  __builtin_amdgcn_global_load_lds((void_g*)(g), (void_l*)(l), 16, 0, 0);
}

// ---- pack x -> bf16 with center padding ----
__global__ __launch_bounds__(256) void pack_x_kernel(const float* __restrict__ x,
                                                     unsigned short* __restrict__ xp) {
  long long t = (long long)blockIdx.x * 256 + threadIdx.x;
  long long base = t * 8;
  if (base >= (long long)NBATCH * PADLEN) return;
  int b   = (int)(base / PADLEN);
  int pos = (int)(base % PADLEN);
  const float* xb = x + (long long)b * XLEN;
  u16x8 v;
#pragma unroll
  for (int j = 0; j < 8; ++j) {
    int xi = pos + j - (NFFT / 2);
    float f = ((unsigned)xi < (unsigned)XLEN) ? xb[xi] : 0.0f;
    v[j] = f2bf(f);
  }
  *reinterpret_cast<u16x8*>(xp + base) = v;
}

// ---- pack W -> bf16 ----
__global__ __launch_bounds__(256) void pack_w_kernel(const float* __restrict__ W,
                                                     unsigned short* __restrict__ Wb) {
  long long t = ((long long)blockIdx.x * 256 + threadIdx.x) * 4;
  if (t >= (long long)NBINS2 * NFFT) return;
  float4 f = *reinterpret_cast<const float4*>(W + t);
  u16x4 v;
  v[0] = f2bf(f.x); v[1] = f2bf(f.y); v[2] = f2bf(f.z); v[3] = f2bf(f.w);
  *reinterpret_cast<u16x4*>(Wb + t) = v;
}

// ---- 256x256 GEMM, 8 waves, per-wave 128x64, 1 barrier/iter, dbuf LDS,
//      T2 swizzle, fused tail for leftover bins/frames ----
__global__ __launch_bounds__(512, 2) void stft_mfma8_kernel(const unsigned short* __restrict__ Xp,
                                                            const unsigned short* __restrict__ Wb,
                                                            float* __restrict__ out) {
  extern __shared__ unsigned short lds[];   // 2 x 64 KiB
  const int tid = threadIdx.x;
  const int l   = tid & 63;
  const int w   = tid >> 6;        // 0..7
  const int wr  = w >> 2;          // 0..1  (M half: 128 rows)
  const int wc  = w & 3;           // 0..3  (N quarter: 64 cols)
  const int r16 = l & 15, hi = l >> 4;

  // XCD swizzle: xcd = bid&7 owns nt in [xcd*8, xcd*8+8) x all 4 mt
  const int bid = blockIdx.x;
  const int c   = bid >> 3;                 // 0..31
  const int nt  = (bid & 7) * 8 + (c & 7);  // 0..63
  const int mt  = c >> 3;                   // 0..3
  const int bin0 = mt * 256;
  const int gf0  = nt * 256;

  // ---- staging: 8 gloads/wave (4 A-chunks + 4 B-chunks of 8 rows each) ----
  const int lr = l >> 3;           // row within 8-row chunk
  const int ls = l & 7;            // 16B slot
  const int cswz = ((ls ^ lr) << 3);   // pre-swizzled source col (elems)

  unsigned aoff[4], boff[4];
#pragma unroll
  for (int j = 0; j < 4; ++j) {
    const int row = (w * 4 + j) * 8 + lr;          // 0..255
    aoff[j] = (unsigned)(bin0 + row) * NFFT + cswz;
    const int gf = gf0 + row;                      // < 16384 always
    const int bb = gf / NFRAMES;
    const int fr = gf - bb * NFRAMES;
    boff[j] = (unsigned)bb * PADLEN + (unsigned)fr * HOPSZ + cswz;
  }

#define STAGE(BUF) do { \
    _Pragma("unroll") \
    for (int j = 0; j < 4; ++j) { \
      gload_lds16(Wb + aoff[j], (BUF) + (w * 4 + j) * 512); \
      gload_lds16(Xp + boff[j], (BUF) + 16384 + (w * 4 + j) * 512); \
      aoff[j] += KT; boff[j] += KT; \
    } } while (0)

  // ---- fragment read bases (T2 XOR-swizzle, row stride 128 B, 8 slots) ----
  const int aB0 = (wr * 128 + r16) * 128;            // + m*2048
  const int bB0 = ABYTES + (wc * 64 + r16) * 128;    // + n*2048
  const int swz = (r16 & 7) << 4;
  const int c0  = (hi * 16) ^ swz;                   // ks0
  const int c1  = (64 + hi * 16) ^ swz;              // ks1

#define RD_F(BASE, AA, BB, C) do { \
    _Pragma("unroll") \
    for (int n_ = 0; n_ < 4; ++n_) \
      BB[n_] = *reinterpret_cast<const bf16x8*>((const char*)(BASE) + bB0 + n_ * 2048 + (C)); \
    _Pragma("unroll") \
    for (int m_ = 0; m_ < 8; ++m_) \
      AA[m_] = *reinterpret_cast<const bf16x8*>((const char*)(BASE) + aB0 + m_ * 2048 + (C)); \
    } while (0)

#define MFMA8(AA, BB, MLO) do { \
    __builtin_amdgcn_s_setprio(1); \
    _Pragma("unroll") \
    for (int m_ = 0; m_ < 4; ++m_) { \
      _Pragma("unroll") \
      for (int n_ = 0; n_ < 4; ++n_) \
        acc[(MLO) + m_][n_] = __builtin_amdgcn_mfma_f32_16x16x32_bf16(AA[(MLO) + m_], BB[n_], acc[(MLO) + m_][n_], 0, 0, 0); \
    } \
    __builtin_amdgcn_s_setprio(0); } while (0)

  f32x4 acc[8][4] = {};
  bf16x8 FaA[8], FaB[4], FbA[8], FbB[4];

  // ---- prologue: stage tile 0, read its ks0 frags ----
  STAGE(lds);
  asm volatile("s_waitcnt vmcnt(0)" ::: "memory");
  __builtin_amdgcn_s_barrier();
  __builtin_amdgcn_sched_barrier(0);
  RD_F(lds, FaA, FaB, c0);

  for (int t = 0; t < NKT; ++t) {
    unsigned short* base = lds + (t & 1) * BUFE;
    unsigned short* nb   = lds + ((t + 1) & 1) * BUFE;

    // P0: wait Fa; stage next tile; MFMA acc[0..3] x ks0
    asm volatile("s_waitcnt lgkmcnt(0)" ::: "memory");
    __builtin_amdgcn_sched_barrier(0);
    if (t < NKT - 1) STAGE(nb);
    MFMA8(FaA, FaB, 0);

    // P1: issue ks1 frag reads; MFMA acc[4..7] x ks0
    RD_F(base, FbA, FbB, c1);
    MFMA8(FaA, FaB, 4);

    // P2: wait Fb; MFMA acc[0..3] x ks1
    asm volatile("s_waitcnt lgkmcnt(0)" ::: "memory");
    __builtin_amdgcn_sched_barrier(0);
    MFMA8(FbA, FbB, 0);

    // P3: drain stage; barrier; read next tile ks0; MFMA acc[4..7] x ks1
    asm volatile("s_waitcnt vmcnt(0)" ::: "memory");
    __builtin_amdgcn_sched_barrier(0);
    __builtin_amdgcn_s_barrier();
    __builtin_amdgcn_sched_barrier(0);
    if (t < NKT - 1) RD_F(nb, FaA, FaB, c0);
    MFMA8(FbA, FbB, 4);
  }

  // ---- epilogue: D row = bin (rbase+r), col = frame (l&15) ----
  const int col   = l & 15;
  const int rbase = (l >> 4) * 4;
#pragma unroll
  for (int m = 0; m < 8; ++m) {
#pragma unroll
    for (int n = 0; n < 4; ++n) {
      const int gf = gf0 + wc * 64 + n * 16 + col;     // < 16384
      const int bb = gf / NFRAMES;
      const int fr = gf - bb * NFRAMES;
#pragma unroll
      for (int r = 0; r < 4; ++r) {
        const int bin = bin0 + wr * 128 + m * 16 + rbase + r;  // < 1024
        size_t off;
        if (bin < FBIN) off = ((size_t)bb * FBIN + bin) * NFRAMES + fr;
        else            off = TOTOUT + ((size_t)bb * FBIN + (bin - FBIN)) * NFRAMES + fr;
        out[off] = acc[m][n][r];
      }
    }
  }

  // ---- fused tail: bins 1024-1025 x gf 0..16399, and bins 0..1023 x gf 16384..16399 ----
  {
    const int gtid = bid * 512 + tid;
    if (gtid < NTAIL) {
      int bin, gf;
      if (gtid < 2 * NGF) { bin = 1024 + (gtid & 1); gf = gtid >> 1; }
      else { const int s = gtid - 2 * NGF; gf = 16384 + (s & 15); bin = s >> 4; }
      const int bb = gf / NFRAMES;
      const int fr = gf - bb * NFRAMES;
      const unsigned short* xr = Xp + (size_t)bb * PADLEN + (size_t)fr * HOPSZ;
      const unsigned short* wrow = Wb + (size_t)bin * NFFT;
      float s0 = 0.f, s1 = 0.f;
      for (int k = 0; k < NFFT; k += 8) {
        u16x8 xv = *reinterpret_cast<const u16x8*>(xr + k);
        u16x8 wv = *reinterpret_cast<const u16x8*>(wrow + k);
#pragma unroll
        for (int j = 0; j < 8; j += 2) {
          s0 = fmaf(bf2f(xv[j]),     bf2f(wv[j]),     s0);
          s1 = fmaf(bf2f(xv[j + 1]), bf2f(wv[j + 1]), s1);
        }
      }
      const float s = s0 + s1;
      size_t off;
      if (bin < FBIN) off = ((size_t)bb * FBIN + bin) * NFRAMES + fr;
      else            off = TOTOUT + ((size_t)bb * FBIN + (bin - FBIN)) * NFRAMES + fr;
      out[off] = s;
    }
  }
#undef STAGE
#undef RD_F
#undef MFMA8
}

// ---- exact f32 direct kernel: fallback only ----
__global__ void stft_direct_kernel(const float* __restrict__ x, const float* __restrict__ W,
                                   float* __restrict__ out,
                                   int bin_lo, int nbins, int fr_lo, int nframes) {
  long long total = (long long)NBATCH * nbins * nframes;
  for (long long t = (long long)blockIdx.x * blockDim.x + threadIdx.x; t < total;
       t += (long long)gridDim.x * blockDim.x) {
    int fr = fr_lo + (int)(t % nframes);
    long long q = t / nframes;
    int bin = bin_lo + (int)(q % nbins);
    int b   = (int)(q / nbins);
    const float* xb = x + (long long)b * XLEN;
    const float* wrow = W + (long long)bin * NFFT;
    float s = 0.f;
    const int base = fr * HOPSZ - (NFFT / 2);
    for (int j = 0; j < NFFT; ++j) {
      int xi = base + j;
      float xv = ((unsigned)xi < (unsigned)XLEN) ? xb[xi] : 0.f;
      s = fmaf(xv, wrow[j], s);
    }
    size_t off;
    if (bin < FBIN) off = ((size_t)b * FBIN + bin) * NFRAMES + fr;
    else            off = TOTOUT + ((size_t)b * FBIN + (bin - FBIN)) * NFRAMES + fr;
    out[off] = s;
  }
}

extern "C" void kernel_launch(void* const* d_in, const int* in_sizes, int n_in,
                              void* d_out, int out_size, void* d_ws, size_t ws_size,
                              hipStream_t stream) {
  const float* x = (const float*)d_in[0];
  const float* W = (const float*)d_in[1];
  float* out = (float*)d_out;

  const size_t xp_bytes = (size_t)NBATCH * PADLEN * sizeof(unsigned short);
  const size_t wb_bytes = (size_t)NBINS2 * NFFT * sizeof(unsigned short);

  if (ws_size >= xp_bytes + wb_bytes) {
    unsigned short* xp = (unsigned short*)d_ws;
    unsigned short* wb = (unsigned short*)((char*)d_ws + xp_bytes);

    {
      long long threads = (long long)NBATCH * PADLEN / 8;
      pack_x_kernel<<<(int)((threads + 255) / 256), 256, 0, stream>>>(x, xp);
    }
    pack_w_kernel<<<(NBINS2 * NFFT / 4 + 255) / 256, 256, 0, stream>>>(W, wb);

    stft_mfma8_kernel<<<NWG, 512, 2 * BUFB, stream>>>(xp, wb, out);
  } else {
    stft_direct_kernel<<<2048, 256, 0, stream>>>(x, W, out, 0, NBINS2, 0, NFRAMES);
  }
}